// Round 1
// baseline (337.777 us; speedup 1.0000x reference)
//
#include <hip/hip_runtime.h>
#include <cmath>

// I/O fp32; internal bf16 MFMA with fp32 accumulate. ws: bf16 intermediates (64 MB).
using u16 = unsigned short;
typedef u16    u16x4  __attribute__((ext_vector_type(4)));
typedef u16    u16x8  __attribute__((ext_vector_type(8)));
typedef __bf16 bf16x8 __attribute__((ext_vector_type(8)));
typedef float  f32x4  __attribute__((ext_vector_type(4)));

constexpr int Bc  = 2;
constexpr int Lc  = 2048;
constexpr int Dc  = 2048;
constexpr int NHc = 16;
constexpr int NKVc= 8;
constexpr int HDc = 128;

__device__ __forceinline__ u16 f2b(float f) {
  union { float f; unsigned u; } v; v.f = f;
  unsigned r = v.u + 0x7FFFu + ((v.u >> 16) & 1u);  // RNE
  return (u16)(r >> 16);
}
__device__ __forceinline__ u16 f2b_fast(float f) {   // round-to-nearest (no NE tie)
  union { float f; unsigned u; } v; v.f = f;
  return (u16)((v.u + 0x8000u) >> 16);
}
__device__ __forceinline__ float b2f(u16 s) {
  union { unsigned u; float f; } v; v.u = ((unsigned)s) << 16;
  return v.f;
}
__device__ __forceinline__ bf16x8 ld_frag(const u16* p) {
  u16x8 u = *(const u16x8*)p;
  return __builtin_bit_cast(bf16x8, u);
}
// async global->LDS, 16 B per lane; LDS dest = uniform base + lane*16
__device__ __forceinline__ void gld_lds16(u16* ldst, const u16* gsrc) {
  __builtin_amdgcn_global_load_lds(
      (const __attribute__((address_space(1))) void*)gsrc,
      (__attribute__((address_space(3))) void*)ldst, 16, 0, 0);
}

// fp32 -> bf16 copy
__global__ void cvt_f32_bf16(const float* __restrict__ src, u16* __restrict__ dst, int n) {
  int i = (blockIdx.x * blockDim.x + threadIdx.x) * 4;
  if (i >= n) return;
  float4 v = *(const float4*)&src[i];
  u16x4 o = { f2b(v.x), f2b(v.y), f2b(v.z), f2b(v.w) };
  *(u16x4*)&dst[i] = o;
}

// fused fp32->bf16 for Wq|Wk|Wv into concatenated Wcat
__global__ void cvt_w3(const float* __restrict__ Wq, const float* __restrict__ Wk,
                       const float* __restrict__ Wv, u16* __restrict__ dst) {
  const int n1 = Dc * Dc;                  // 4194304
  const int n2 = n1 + (NKVc*HDc) * Dc;     // +2097152
  const int n3 = n2 + (NKVc*HDc) * Dc;
  int i = (blockIdx.x * blockDim.x + threadIdx.x) * 4;
  if (i >= n3) return;
  const float* src; int off;
  if (i < n1)      { src = Wq; off = i; }
  else if (i < n2) { src = Wk; off = i - n1; }
  else             { src = Wv; off = i - n2; }
  float4 v = *(const float4*)&src[off];
  u16x4 o = { f2b(v.x), f2b(v.y), f2b(v.z), f2b(v.w) };
  *(u16x4*)&dst[i] = o;
}

// ===========================================================================
// 256x256-tile QKV GEMM, BK=32, 4-slot LDS ring (128 KB), prefetch depth 3,
// counted vmcnt(8) (never 0 in main loop), setprio around the MFMA cluster.
// 512 threads = 8 waves (2M x 4N); per-wave output 128x64 = acc[8][4].
// LDS swizzle: phys col-group = cg ^ ((row>>1)&3), applied on the global
// SOURCE address for global_load_lds (linear LDS dest) and on ds_read.
// Epilogue routes n<2048 -> Qp, <3072 -> Kp, else Vt (transposed via LDS).
// ===========================================================================
__device__ __forceinline__ void stage_tile32(u16* lds, const u16* __restrict__ A,
    const u16* __restrict__ W, int slot, int kt, int m0, int n0, int wave, int lane)
{
  const int srow = lane >> 2;          // row within 16-row chunk
  const int scg  = lane & 3;           // physical col-group this lane fills
  const int skey = (lane >> 3) & 3;    // == (row>>1)&3 for this lane's row
  const int sb   = slot * 16384;       // u16 units; slot = A 8192 + B 8192
#pragma unroll
  for (int i = 0; i < 2; ++i) {
    int c = wave + i * 8;              // 16-row chunk index, 0..15
    int row = c * 16 + srow;
    gld_lds16(&lds[sb + c * 512],
              &A[(size_t)(m0 + row) * Dc + kt * 32 + (scg ^ skey) * 8]);
    gld_lds16(&lds[sb + 8192 + c * 512],
              &W[(size_t)(n0 + row) * Dc + kt * 32 + (scg ^ skey) * 8]);
  }
}

__device__ __forceinline__ void compute_tile32(const u16* lds, int slot,
    int wm, int wn, int quad, int l16, f32x4 acc[8][4])
{
  const u16* sA = lds + slot * 16384;
  const u16* sB = sA + 8192;
  const int pcg = (quad ^ ((l16 >> 1) & 3)) * 8;   // swizzled ds_read col
  bf16x8 af[8], bfr[4];
#pragma unroll
  for (int mi = 0; mi < 8; ++mi)
    af[mi] = ld_frag(&sA[(wm * 128 + mi * 16 + l16) * 32 + pcg]);
#pragma unroll
  for (int ni = 0; ni < 4; ++ni)
    bfr[ni] = ld_frag(&sB[(wn * 64 + ni * 16 + l16) * 32 + pcg]);
  __builtin_amdgcn_s_setprio(1);
#pragma unroll
  for (int mi = 0; mi < 8; ++mi)
#pragma unroll
    for (int ni = 0; ni < 4; ++ni)
      acc[mi][ni] = __builtin_amdgcn_mfma_f32_16x16x32_bf16(af[mi], bfr[ni], acc[mi][ni], 0, 0, 0);
  __builtin_amdgcn_s_setprio(0);
}

__global__ __launch_bounds__(512, 2) void gemm256_qkv(
    const u16* __restrict__ A, const u16* __restrict__ W,
    u16* __restrict__ Qp, u16* __restrict__ Kp, u16* __restrict__ Vtp)
{
  __shared__ u16 lds[65536];           // 128 KB: 4 ring slots x (A 16KB + B 16KB)
  const int tid  = threadIdx.x;
  const int wave = tid >> 6, lane = tid & 63;
  const int quad = lane >> 4, l16 = lane & 15;
  // XCD-chunked swizzle (256 blocks, nwg%8==0 -> simple form is bijective)
  const int bid = blockIdx.x;
  const int swz = (bid & 7) * 32 + (bid >> 3);
  const int tx = swz & 15, ty = swz >> 4;
  const int m0 = ty * 256, n0 = tx * 256;
  const int wm = wave >> 2, wn = wave & 3;

  f32x4 acc[8][4];
#pragma unroll
  for (int i = 0; i < 8; ++i)
#pragma unroll
    for (int j = 0; j < 4; ++j) acc[i][j] = {0.f, 0.f, 0.f, 0.f};

  // prologue: 3 tiles in flight (12 loads/wave)
  stage_tile32(lds, A, W, 0, 0, m0, n0, wave, lane);
  stage_tile32(lds, A, W, 1, 1, m0, n0, wave, lane);
  stage_tile32(lds, A, W, 2, 2, m0, n0, wave, lane);

  // K = 2048 -> 64 K-tiles of 32. Steady state: wait retires tile kt (issued
  // 3 iters ago, already landed), 8 loads (tiles kt+1,kt+2) stay in flight.
  for (int kt = 0; kt < 61; ++kt) {
    __asm__ volatile("s_waitcnt vmcnt(8)\n\ts_barrier" ::: "memory");
    stage_tile32(lds, A, W, (kt + 3) & 3, kt + 3, m0, n0, wave, lane);
    compute_tile32(lds, kt & 3, wm, wn, quad, l16, acc);
  }
  __asm__ volatile("s_waitcnt vmcnt(8)\n\ts_barrier" ::: "memory");
  compute_tile32(lds, 1, wm, wn, quad, l16, acc);   // kt=61
  __asm__ volatile("s_waitcnt vmcnt(4)\n\ts_barrier" ::: "memory");
  compute_tile32(lds, 2, wm, wn, quad, l16, acc);   // kt=62
  __asm__ volatile("s_waitcnt vmcnt(0)\n\ts_barrier" ::: "memory");
  compute_tile32(lds, 3, wm, wn, quad, l16, acc);   // kt=63

  // ---- epilogue: C/D layout col = l16 (n), row = quad*4+r (m) ----
  if (n0 < 3072) {
    u16* Cb; int ldc, nc0;
    if (n0 < 2048) { Cb = Qp; ldc = 2048; nc0 = n0; }
    else           { Cb = Kp; ldc = 1024; nc0 = n0 - 2048; }
#pragma unroll
    for (int mi = 0; mi < 8; ++mi)
#pragma unroll
      for (int ni = 0; ni < 4; ++ni)
#pragma unroll
        for (int r = 0; r < 4; ++r) {
          int m = m0 + wm * 128 + mi * 16 + quad * 4 + r;
          int n = nc0 + wn * 64 + ni * 16 + l16;
          Cb[(size_t)m * ldc + n] = f2b(acc[mi][ni][r]);
        }
  } else {
    // V block (n 3072..4095 = 2 kv heads per tile): transpose 256x256 via LDS.
    __syncthreads();                   // all tile reads retired; reuse full LDS
#pragma unroll
    for (int mi = 0; mi < 8; ++mi)
#pragma unroll
      for (int ni = 0; ni < 4; ++ni)
#pragma unroll
        for (int r = 0; r < 4; ++r) {
          int l = wm * 128 + mi * 16 + quad * 4 + r;     // 0..255 (seq pos)
          int d = wn * 64 + ni * 16 + l16;               // 0..255 (2 heads x 128)
          lds[l * 256 + (((d >> 3) ^ (l & 31)) << 3) + (d & 7)] = f2b(acc[mi][ni][r]);
        }
    __syncthreads();
    const int b    = m0 >> 11;
    const int hkv0 = (n0 - 3072) >> 7;
#pragma unroll
    for (int it = 0; it < 16; ++it) {
      int sl = tid + it * 512;         // 0..8191
      int dl = sl >> 5;                // 0..255
      int lc = (sl & 31) * 8;          // 0..248
      u16x8 v;
#pragma unroll
      for (int e = 0; e < 8; ++e) {
        int l = lc + e;
        v[e] = lds[l * 256 + (((dl >> 3) ^ (l & 31)) << 3) + (dl & 7)];
      }
      const int hkv = hkv0 + (dl >> 7);
      const int d   = dl & 127;
      *(u16x8*)&Vtp[(((size_t)b * NKVc + hkv) * HDc + d) * (size_t)Lc + (m0 & (Lc - 1)) + lc] = v;
    }
  }
}

// C[M,N] = A[M,K] @ W[N,K]^T, bf16 in, fp32 out. 128x128 tile, BK=64,
// global_load_lds staging, column-group XOR swizzle. (Output projection.)
__global__ __launch_bounds__(256) void gemm_out(
    const u16* __restrict__ A, const u16* __restrict__ W,
    float* __restrict__ Cf, int M, int N, int K)
{
  __shared__ u16 lds[16384];         // lA = [0,8192), lB = [8192,16384); 32 KB
  u16* lA = lds;
  u16* lB = lds + 8192;
  const int tid  = threadIdx.x;
  const int wave = tid >> 6, lane = tid & 63;
  const int quad = lane >> 4, l16 = lane & 15;
  const int t7   = l16 & 7;
  const int m0 = blockIdx.y * 128, n0 = blockIdx.x * 128;
  const int mw = (wave >> 1) * 64, nw = (wave & 1) * 64;
  const int r8 = lane >> 3;                      // row-in-chunk
  const int cgl = (lane & 7) ^ r8;               // swizzled source col-group

  f32x4 acc[4][4];
#pragma unroll
  for (int i = 0; i < 4; ++i)
#pragma unroll
    for (int j = 0; j < 4; ++j) acc[i][j] = {0.f, 0.f, 0.f, 0.f};

  for (int kt = 0; kt < K; kt += 64) {
#pragma unroll
    for (int cc = 0; cc < 4; ++cc) {             // 16 chunks of 8 rows, 4 per wave
      int c = wave + cc * 4;
      gld_lds16(&lA[c * 512], &A[(size_t)(m0 + 8 * c + r8) * K + kt + cgl * 8]);
      gld_lds16(&lB[c * 512], &W[(size_t)(n0 + 8 * c + r8) * K + kt + cgl * 8]);
    }
    __syncthreads();
#pragma unroll
    for (int s = 0; s < 2; ++s) {
      bf16x8 af[4], bf[4];
#pragma unroll
      for (int i = 0; i < 4; ++i)
        af[i] = ld_frag(&lA[(mw + i*16 + l16) * 64 + ((quad + 4*s) ^ t7) * 8]);
#pragma unroll
      for (int j = 0; j < 4; ++j)
        bf[j] = ld_frag(&lB[(nw + j*16 + l16) * 64 + ((quad + 4*s) ^ t7) * 8]);
#pragma unroll
      for (int i = 0; i < 4; ++i)
#pragma unroll
        for (int j = 0; j < 4; ++j)
          acc[i][j] = __builtin_amdgcn_mfma_f32_16x16x32_bf16(af[i], bf[j], acc[i][j], 0, 0, 0);
    }
    __syncthreads();
  }

  // C/D layout: col = lane&15 (n), row = quad*4+r (m)
#pragma unroll
  for (int i = 0; i < 4; ++i)
#pragma unroll
    for (int j = 0; j < 4; ++j)
#pragma unroll
      for (int r = 0; r < 4; ++r) {
        int m = m0 + mw + i*16 + quad*4 + r;
        int n = n0 + nw + j*16 + l16;
        Cf[(size_t)m * N + n] = acc[i][j][r];
      }
}

// Fused RoPE over Q (scaled by qs) and K (unscaled), single launch.
__global__ void rope2_kernel(u16* __restrict__ Qp, u16* __restrict__ Kp, float qs)
{
  const int nQ = Bc * Lc * NHc * 64;
  const int nT = nQ + Bc * Lc * NKVc * 64;
  int t = blockIdx.x * blockDim.x + threadIdx.x;
  if (t >= nT) return;
  u16* T; int nheads; float osc; int idx;
  if (t < nQ) { T = Qp; nheads = NHc;  osc = qs;  idx = t; }
  else        { T = Kp; nheads = NKVc; osc = 1.f; idx = t - nQ; }
  int d   = idx & 63;
  int h   = (idx >> 6) % nheads;
  int row = idx / (nheads * 64);
  int l   = row & (Lc - 1);
  float freq = exp2f((float)d * (-13.287712379549449f / 64.f));  // theta^(-d/64)
  float ang  = (float)l * freq;
  float s, c;
  sincosf(ang, &s, &c);
  size_t base = (size_t)row * (nheads * 128) + h * 128;
  float x1 = b2f(T[base + d]);
  float x2 = b2f(T[base + d + 64]);
  T[base + d]      = f2b((x1 * c - x2 * s) * osc);
  T[base + d + 64] = f2b((x2 * c + x1 * s) * osc);
}

// Causal GQA flash attention, merged GQA pair (2 query heads per KV head per
// block), DMA-pipelined, softmax-lite.
__global__ __launch_bounds__(512) void flash_kernel(
    const u16* __restrict__ Q, const u16* __restrict__ K, const u16* __restrict__ Vt,
    u16* __restrict__ O)
{
  __shared__ u16 smem[41984];        // 82 KB
  const int tid  = threadIdx.x;
  const int wave = tid >> 6, lane = tid & 63;
  const int quad = lane >> 4, l16 = lane & 15;
  const int hw = wave >> 2, wr = wave & 3;     // head-within-pair, wave-within-head
  const int bhkv = blockIdx.x;
  const int b = bhkv >> 3, hkv = bhkv & 7;
  const int h = hkv * 2 + hw;

  const size_t kbase = ((size_t)b * Lc) * (NKVc * HDc) + (size_t)hkv * HDc;
  const size_t vbase = (((size_t)b * NKVc + hkv) * HDc) * (size_t)Lc;

  const int kr8 = lane >> 4;             // K: row in 4-row chunk
  const int kcl = lane & 15;             // K: physical col-group
  const int vr16 = lane >> 3;            // V: row in 8-row chunk
  const int vkl  = lane & 7;             // V: physical key-group

  u16* sP_w = smem + 32768 + wave * 1152;

  for (int pass = 0; pass < 2; ++pass) {
    const int qt = (pass == 0) ? (31 - (int)blockIdx.y) : (int)blockIdx.y;
    const int q0 = qt * 64;

    __syncthreads();                     // prev pass LDS fully retired
    // ---- stage Q both heads (128 x 128 logical) into K0+K1 region, swizzled ----
#pragma unroll
    for (int i = 0; i < 4; ++i) {
      int g = tid + i * 512;
      int row = g >> 4, cg = g & 15;     // row 0..127: head = row>>6, local = row&63
      int qh = hkv * 2 + (row >> 6);
      int rr = row & 63;
      *(u16x8*)&smem[row * 128 + (cg ^ (row & 15)) * 8] =
          *(const u16x8*)&Q[((size_t)(b * Lc + q0 + rr)) * Dc + (size_t)qh * HDc + cg * 8];
    }
    __syncthreads();
    bf16x8 qf[4];
#pragma unroll
    for (int ks = 0; ks < 4; ++ks)
      qf[ks] = ld_frag(&smem[(hw*64 + wr*16 + l16) * 128 + ((ks*4 + quad) ^ l16) * 8]);
    __syncthreads();                     // qf extracted before K(0) DMA overwrites

    // ---- prologue: issue K(0) then V(0), 2 chunks per wave each ----
#pragma unroll
    for (int i = 0; i < 2; ++i) {
      int c = wave + i * 8;
      int row = c * 4 + kr8;
      gld_lds16(smem + c * 512,
                &K[kbase + (size_t)row * (NKVc*HDc) + (size_t)(kcl ^ (row & 15)) * 8]);
    }
#pragma unroll
    for (int i = 0; i < 2; ++i) {
      int c = wave + i * 8;
      int d = c * 8 + vr16;
      gld_lds16(smem + 16384 + c * 512,
                &Vt[vbase + (size_t)d * Lc + (size_t)(vkl ^ (d & 7)) * 8]);
    }

    f32x4 acc_o[8];
#pragma unroll
    for (int i = 0; i < 8; ++i) acc_o[i] = {0.f, 0.f, 0.f, 0.f};
    float ps[4] = {0.f, 0.f, 0.f, 0.f};

    for (int kt = 0; kt <= qt; ++kt) {
      const int kOff  = (kt & 1) ? 8192 : 0;
      const int kOffN = (kt & 1) ? 0 : 8192;
      const int vOff  = (kt & 1) ? 24576 : 16384;
      const int vOffN = (kt & 1) ? 16384 : 24576;

      // TOP: wait K(kt) (2 oldest in per-wave FIFO), barrier; asm = fence
      __asm__ volatile("s_waitcnt vmcnt(2)\n\ts_barrier" ::: "memory");

      if (kt < qt) {                     // issue K(kt+1)
#pragma unroll
        for (int i = 0; i < 2; ++i) {
          int c = wave + i * 8;
          int row = (kt + 1) * 64 + c * 4 + kr8;
          gld_lds16(smem + kOffN + c * 512,
                    &K[kbase + (size_t)row * (NKVc*HDc) + (size_t)(kcl ^ (row & 15)) * 8]);
        }
      }

      // ---- S = Q K^T (16 x 64 per wave) ----
      const u16* sKc = smem + kOff;
      f32x4 accs[4];
#pragma unroll
      for (int n = 0; n < 4; ++n) accs[n] = {0.f, 0.f, 0.f, 0.f};
#pragma unroll
      for (int ks = 0; ks < 4; ++ks)
#pragma unroll
        for (int n = 0; n < 4; ++n) {
          bf16x8 kf = ld_frag(&sKc[(n*16 + l16) * 128 + ((ks*4 + quad) ^ l16) * 8]);
          accs[n] = __builtin_amdgcn_mfma_f32_16x16x32_bf16(qf[ks], kf, accs[n], 0, 0, 0);
        }

      // ---- softmax-lite: p = exp2(s); only diagonal tile masked ----
      const int qrow = q0 + wr*16 + quad*4;
      if (kt == qt) {
#pragma unroll
        for (int n = 0; n < 4; ++n) {
          int kg = kt*64 + n*16 + l16;
#pragma unroll
          for (int r = 0; r < 4; ++r)
            if (kg > qrow + r) accs[n][r] = -INFINITY;
        }
      }
#pragma unroll
      for (int n = 0; n < 4; ++n)
#pragma unroll
        for (int r = 0; r < 4; ++r) {
          float p = exp2f(accs[n][r]);   // exp2(-inf) = 0 for masked
          accs[n][r] = p;
          ps[r] += p;
        }

      // P (C-layout) -> wave-private LDS (A-layout readable)
#pragma unroll
      for (int n = 0; n < 4; ++n)
#pragma unroll
        for (int r = 0; r < 4; ++r)
          sP_w[(quad*4 + r) * 72 + n*16 + l16] = f2b_fast(accs[n][r]);

      // MID: wait V(kt) + own P ds_writes, barrier
      if (kt < qt)
        __asm__ volatile("s_waitcnt vmcnt(2) lgkmcnt(0)\n\ts_barrier" ::: "memory");
      else
        __asm__ volatile("s_waitcnt vmcnt(0) lgkmcnt(0)\n\ts_barrier" ::: "memory");

      if (kt < qt) {                     // issue V(kt+1)
#pragma unroll
        for (int i = 0; i < 2; ++i) {
          int c = wave + i * 8;
          int d = c * 8 + vr16;
          gld_lds16(smem + vOffN + c * 512,
                    &Vt[vbase + (size_t)d * Lc + (kt+1)*64 + (size_t)(vkl ^ (d & 7)) * 8]);
        }
      }

      // ---- O += P V ----
      const u16* sVc = smem + vOff;
#pragma unroll
      for (int s2 = 0; s2 < 2; ++s2) {
        bf16x8 pf = ld_frag(&sP_w[l16 * 72 + s2*32 + quad*8]);
#pragma unroll
        for (int di = 0; di < 8; ++di) {
          bf16x8 vf = ld_frag(&sVc[(di*16 + l16) * 64 + ((s2*4 + quad) ^ (l16 & 7)) * 8]);
          acc_o[di] = __builtin_amdgcn_mfma_f32_16x16x32_bf16(pf, vf, acc_o[di], 0, 0, 0);
        }
      }
    }

    // ---- final l reduction + epilogue ----
#pragma unroll
    for (int off = 1; off < 16; off <<= 1)
#pragma unroll
      for (int r = 0; r < 4; ++r) ps[r] += __shfl_xor(ps[r], off);
    float inv[4];
#pragma unroll
    for (int r = 0; r < 4; ++r) inv[r] = 1.0f / ps[r];

#pragma unroll
    for (int di = 0; di < 8; ++di)
#pragma unroll
      for (int r = 0; r < 4; ++r) {
        int qrow = q0 + wr*16 + quad*4 + r;
        int d = di*16 + l16;
        float v = acc_o[di][r] * inv[r];
        O[((size_t)(b * Lc + qrow)) * Dc + (size_t)h * HDc + d] = f2b(v);
      }
  }
}

extern "C" void kernel_launch(void* const* d_in, const int* in_sizes, int n_in,
                              void* d_out, int out_size, void* d_ws, size_t ws_size,
                              hipStream_t stream)
{
  const float* x  = (const float*)d_in[0];
  const float* Wq = (const float*)d_in[1];
  const float* Wk = (const float*)d_in[2];
  const float* Wv = (const float*)d_in[3];
  const float* Wo = (const float*)d_in[4];
  float* out = (float*)d_out;

  const int M = Bc * Lc;                         // 4096
  u16* ws = (u16*)d_ws;
  u16* xb   = ws;                                // [4096][2048]  (reused as Ow)
  u16* Ow   = xb;
  u16* Wcat = ws + (size_t)8 * 1024 * 1024;      // [4096][2048]  (reused as Wob)
  u16* Wob  = Wcat;
  u16* Qw   = Wcat + (size_t)8 * 1024 * 1024;    // [4096][2048]
  u16* Kw   = Qw   + (size_t)8 * 1024 * 1024;    // [4096][1024]
  u16* Vt   = Kw   + (size_t)4 * 1024 * 1024;    // [2][8][128][2048]

  const int nx = M * Dc;
  const int nq = Dc * Dc;
  const int nw3 = nq + 2 * (NKVc*HDc) * Dc;      // Wq+Wk+Wv elems
  cvt_f32_bf16<<<nx/1024, 256, 0, stream>>>(x, xb, nx);
  cvt_w3<<<nw3/1024, 256, 0, stream>>>(Wq, Wk, Wv, Wcat);

  // 256 blocks = 1/CU; 16x16 tiles of 256x256 over [4096][4096]
  gemm256_qkv<<<256, 512, 0, stream>>>(xb, Wcat, Qw, Kw, Vt);

  // Q pre-scaled by SCALE*log2(e) so flash softmax runs in exp2 domain.
  const float qs = 0.08838834764831845f * 1.4426950408889634f;
  const int nrope = M * (NHc + NKVc) * 64;
  rope2_kernel<<<(nrope + 255) / 256, 256, 0, stream>>>(Qw, Kw, qs);

  flash_kernel<<<dim3(Bc*NKVc, 16), 512, 0, stream>>>(Qw, Kw, Vt, Ow);

  cvt_f32_bf16<<<nq/1024, 256, 0, stream>>>(Wo, Wob, nq);
  gemm_out<<<dim3(16, 32), 256, 0, stream>>>(Ow, Wob, out, M, Dc, Dc);
}